// Round 3
// baseline (3404.332 us; speedup 1.0000x reference)
//
#include <hip/hip_runtime.h>
#include <hip/hip_bf16.h>

typedef __hip_bfloat16 bf16;

__device__ __forceinline__ float b2f(bf16 v){ return __bfloat162float(v); }

__device__ __forceinline__ float wred_sum(float v){
  #pragma unroll
  for (int o = 32; o > 0; o >>= 1) v += __shfl_xor(v, o, 64);
  return v;
}
__device__ __forceinline__ float wred_max(float v){
  #pragma unroll
  for (int o = 32; o > 0; o >>= 1) v = fmaxf(v, __shfl_xor(v, o, 64));
  return v;
}

// ---------------------------------------------------------------------------
// Kernel 1: modality projections -> relu -> l2norm -> phase mul (pure states)
// grid 256 (bt), block 128
// ---------------------------------------------------------------------------
template<int DIMN>
__device__ void modality(const float* x, const float* W, const float* bia, const float* ph,
                         float* PURE, float* RNORM, int m, float* xs, float* red)
{
  int bt = blockIdx.x, tid = threadIdx.x;
  for (int i = tid; i < DIMN; i += 128) xs[i] = x[bt*DIMN + i];
  __syncthreads();
  float acc = bia[tid];
  for (int k = 0; k < DIMN; k++) acc = fmaf(xs[k], W[k*128 + tid], acc);
  float rep = fmaxf(acc, 0.f);
  float s = wred_sum(rep*rep);
  int wid = tid >> 6, lane = tid & 63;
  if (lane == 0) red[wid] = s;
  __syncthreads();
  float nrm = sqrtf(red[0] + red[1]);
  float amp = rep / fmaxf(nrm, 1e-12f);
  float p = ph[tid];
  PURE[bt*768 + m*128 + tid]       = amp * cosf(p);
  PURE[bt*768 + (3+m)*128 + tid]   = amp * sinf(p);
  if (tid == 0) RNORM[bt*4 + m] = nrm;
  __syncthreads();
}

__global__ void proj_kernel(const float* xt, const float* xv, const float* xa,
    const float* Wt, const float* bt_, const float* Wv, const float* bv,
    const float* Wa, const float* ba, const float* pht, const float* phv, const float* pha,
    float* PURE, float* RNORM)
{
  __shared__ float xs[600];
  __shared__ float red[2];
  modality<600>(xt, Wt, bt_, pht, PURE, RNORM, 0, xs, red);
  modality<342>(xv, Wv, bv,  phv, PURE, RNORM, 1, xs, red);
  modality<300>(xa, Wa, ba,  pha, PURE, RNORM, 2, xs, red);
}

// ---------------------------------------------------------------------------
// Kernel 2: language reps + Hadamard + entanglement (constant over b,t)
// grid 1, block 128.  LANGB: [0..127]=ent_r, [128..255]=ent_i, [256]=||lrep1||
// ---------------------------------------------------------------------------
__global__ void lang_kernel(const float* l1, const float* l2,
    const float* Wl1, const float* bl1, const float* Wl2, const float* bl2,
    const float* pht, float* LANGB)
{
  __shared__ float xs1[300], xs2[300];
  __shared__ float red[4];
  int tid = threadIdx.x;
  for (int i = tid; i < 300; i += 128){ xs1[i] = l1[i]; xs2[i] = l2[i]; }
  __syncthreads();
  float a1 = bl1[tid], a2 = bl2[tid];
  for (int k = 0; k < 300; k++){
    a1 = fmaf(xs1[k], Wl1[k*128 + tid], a1);
    a2 = fmaf(xs2[k], Wl2[k*128 + tid], a2);
  }
  a1 = fmaxf(a1, 0.f); a2 = fmaxf(a2, 0.f);
  int wid = tid >> 6, lane = tid & 63;
  float s1 = wred_sum(a1*a1), s2 = wred_sum(a2*a2);
  if (lane == 0){ red[wid] = s1; red[2+wid] = s2; }
  __syncthreads();
  float n1 = sqrtf(red[0] + red[1]);
  float n2 = sqrtf(red[2] + red[3]);
  float lamp1 = a1 / fmaxf(n1, 1e-12f);
  float lamp2 = a2 / fmaxf(n2, 1e-12f);
  float ph = pht[tid];
  float c = cosf(ph), s = sinf(ph);
  const float s2c = 0.70710678118654752f;
  float h1r = (lamp1*c + lamp1*s)*s2c, h1i = (lamp1*c - lamp1*s)*s2c;
  float h2r = (lamp2*c + lamp2*s)*s2c, h2i = (lamp2*c - lamp2*s)*s2c;
  float er = h1r*h2r - h1i*h2i;
  float ei = h1r*h2i + h1i*h2r;
  __syncthreads();
  float se = wred_sum(er*er + ei*ei);
  if (lane == 0) red[wid] = se;
  __syncthreads();
  float en = fmaxf(sqrtf(red[0] + red[1]), 1e-12f);
  LANGB[tid]       = er / en;
  LANGB[128 + tid] = ei / en;
  if (tid == 0) LANGB[256] = n1;
}

// ---------------------------------------------------------------------------
// Kernel 3: weighted sum of rank-1 density matrices -> X[0:256]=rho_r, X[256:512]=rho_i
// grid 256 (bt), block 256
// ---------------------------------------------------------------------------
__global__ __launch_bounds__(256) void rho_kernel(const float* PURE, const float* RNORM,
                                                  const float* LANGB, float* X)
{
  __shared__ float rv[4][128], iv[4][128], wsm[4];
  int bt = blockIdx.x, tid = threadIdx.x;
  for (int i = tid; i < 1024; i += 256){
    int d = i & 127;
    if (i < 768){ int m = i >> 7; float v = PURE[bt*768 + i];
                  if (m < 3) rv[m][d] = v; else iv[m-3][d] = v; }
    else if (i < 896) rv[3][d] = LANGB[d];
    else              iv[3][d] = LANGB[128 + d];
  }
  if (tid == 0){
    float n0 = RNORM[bt*4+0], n1 = RNORM[bt*4+1], n2 = RNORM[bt*4+2], n3 = LANGB[256];
    float mx = fmaxf(fmaxf(n0, n1), fmaxf(n2, n3));
    float e0 = __expf(n0-mx), e1 = __expf(n1-mx), e2 = __expf(n2-mx), e3 = __expf(n3-mx);
    float inv = 1.f / (e0+e1+e2+e3);
    wsm[0]=e0*inv; wsm[1]=e1*inv; wsm[2]=e2*inv; wsm[3]=e3*inv;
  }
  __syncthreads();
  float w0 = wsm[0], w1 = wsm[1], w2 = wsm[2], w3 = wsm[3];
  for (int idx = tid; idx < 16384; idx += 256){
    int d = idx >> 7, e = idx & 127;
    float rr = 0.f, ri = 0.f;
    {
      float rd=rv[0][d], re=rv[0][e], id=iv[0][d], ie=iv[0][e];
      rr = fmaf(w0, rd*re + id*ie, rr); ri = fmaf(w0, id*re - rd*ie, ri);
    }{
      float rd=rv[1][d], re=rv[1][e], id=iv[1][d], ie=iv[1][e];
      rr = fmaf(w1, rd*re + id*ie, rr); ri = fmaf(w1, id*re - rd*ie, ri);
    }{
      float rd=rv[2][d], re=rv[2][e], id=iv[2][d], ie=iv[2][e];
      rr = fmaf(w2, rd*re + id*ie, rr); ri = fmaf(w2, id*re - rd*ie, ri);
    }{
      float rd=rv[3][d], re=rv[3][e], id=iv[3][d], ie=iv[3][e];
      rr = fmaf(w3, rd*re + id*ie, rr); ri = fmaf(w3, id*re - rd*ie, ri);
    }
    X[(size_t)bt*16384 + idx]        = rr;
    X[(size_t)(256+bt)*16384 + idx]  = ri;
  }
}

// ---------------------------------------------------------------------------
// Kernel 4a: fused MHA per (sequence n, head h). grid (512,4), block 256
// Computes QKV in-kernel, softmax(QK^T)V, writes head slice into ATTO (bf16).
// ---------------------------------------------------------------------------
__global__ __launch_bounds__(256) void attn_kernel(const float* X, const float* Wqkv,
                                                   const float* bqkv, bf16* ATTO)
{
  __shared__ float Qs[128*33], Ks[128*33], Vs[128*33];
  __shared__ float pbuf[4*128];
  int n = blockIdx.x, h = blockIdx.y, tid = threadIdx.x;
  const float* xn = X + (size_t)n*16384;
  int c = tid & 31, r0 = tid >> 5;
  int jq = h*32 + c, jk = 128 + h*32 + c, jv = 256 + h*32 + c;
  for (int rb = 0; rb < 16; rb++){
    int r = rb*8 + r0;
    float aq = bqkv[jq], ak = bqkv[jk], av = bqkv[jv];
    for (int k = 0; k < 128; k++){
      float xv = xn[r*128 + k];
      aq = fmaf(xv, Wqkv[k*384 + jq], aq);
      ak = fmaf(xv, Wqkv[k*384 + jk], ak);
      av = fmaf(xv, Wqkv[k*384 + jv], av);
    }
    Qs[r*33 + c] = aq * 0.17677669529663687f;  // 1/sqrt(32)
    Ks[r*33 + c] = ak;
    Vs[r*33 + c] = av;
  }
  __syncthreads();
  int wid = tid >> 6, lane = tid & 63;
  for (int rr = 0; rr < 32; rr++){
    int r = wid*32 + rr;
    float s1 = 0.f, s2 = 0.f;
    #pragma unroll 8
    for (int k = 0; k < 32; k++){
      float q = Qs[r*33 + k];
      s1 = fmaf(q, Ks[lane*33 + k], s1);
      s2 = fmaf(q, Ks[(lane+64)*33 + k], s2);
    }
    float M = wred_max(fmaxf(s1, s2));
    float p1 = __expf(s1 - M), p2 = __expf(s2 - M);
    float S = wred_sum(p1 + p2);
    float inv = 1.f / S;
    pbuf[wid*128 + lane]      = p1 * inv;
    pbuf[wid*128 + lane + 64] = p2 * inv;
    int cc = lane & 31, jh = lane >> 5;
    float acc = 0.f;
    #pragma unroll 8
    for (int jj = 0; jj < 64; jj++){
      int j = jh*64 + jj;
      acc = fmaf(pbuf[wid*128 + j], Vs[j*33 + cc], acc);
    }
    acc += __shfl_down(acc, 32, 64);
    if (lane < 32) ATTO[(size_t)n*16384 + r*128 + h*32 + cc] = __float2bfloat16(acc);
  }
}

// ---------------------------------------------------------------------------
// Kernel 4b: X = LN(X + SRC@Wo + bo).  grid 512, block 256 (2 rows/iter)
// SRC is bf16 scratch.
// ---------------------------------------------------------------------------
__global__ __launch_bounds__(256) void proj_ln_kernel(const bf16* SRC, float* X,
    const float* Wo, const float* bo, const float* g, const float* bb)
{
  __shared__ float red[8];
  int n = blockIdx.x, tid = threadIdx.x;
  int half = tid >> 7, cc = tid & 127;
  int wid = tid >> 6, lane = tid & 63;
  const bf16* A = SRC + (size_t)n*16384;
  float* xn = X + (size_t)n*16384;
  float gv = g[cc], bv = bb[cc], bov = bo[cc];
  for (int rr = 0; rr < 64; rr++){
    int row = rr*2 + half;
    float acc = bov;
    for (int k = 0; k < 128; k++)
      acc = fmaf(b2f(A[row*128 + k]), Wo[k*128 + cc], acc);
    float y = acc + xn[row*128 + cc];
    float s = wred_sum(y), q = wred_sum(y*y);
    if (lane == 0){ red[wid*2] = s; red[wid*2+1] = q; }
    __syncthreads();
    float S = red[half*4+0] + red[half*4+2];
    float Q = red[half*4+1] + red[half*4+3];
    float m = S * (1.f/128.f);
    float var = Q * (1.f/128.f) - m*m;
    xn[row*128 + cc] = (y - m) * rsqrtf(var + 1e-5f) * gv + bv;
    __syncthreads();
  }
}

// ---------------------------------------------------------------------------
// Kernel 4c: X = LN(X + relu(X@W1+b1)@W2 + b2).  grid 512, block 256, 4 rows/iter
// ---------------------------------------------------------------------------
__global__ __launch_bounds__(256) void ffn_ln_kernel(float* X,
    const float* W1, const float* bf1, const float* W2, const float* bf2,
    const float* g, const float* bb)
{
  __shared__ float hbuf[4*512];
  __shared__ float pt[4*256];
  __shared__ float redS[8], redQ[8];
  int n = blockIdx.x, tid = threadIdx.x;
  int wid = tid >> 6, lane = tid & 63;
  float* xn = X + (size_t)n*16384;
  float b1a = bf1[tid], b1b = bf1[tid+256];
  int cc = tid & 127, hf = tid >> 7;
  float gv = g[cc], bv = bb[cc], b2v = bf2[cc];
  for (int it = 0; it < 32; it++){
    int row0 = it*4;
    float a[4][2];
    #pragma unroll
    for (int ri = 0; ri < 4; ri++){ a[ri][0] = b1a; a[ri][1] = b1b; }
    for (int k = 0; k < 128; k++){
      float w0 = W1[k*512 + tid];
      float w1 = W1[k*512 + tid + 256];
      #pragma unroll
      for (int ri = 0; ri < 4; ri++){
        float xv = xn[(row0+ri)*128 + k];
        a[ri][0] = fmaf(xv, w0, a[ri][0]);
        a[ri][1] = fmaf(xv, w1, a[ri][1]);
      }
    }
    #pragma unroll
    for (int ri = 0; ri < 4; ri++){
      hbuf[ri*512 + tid]       = fmaxf(a[ri][0], 0.f);
      hbuf[ri*512 + tid + 256] = fmaxf(a[ri][1], 0.f);
    }
    __syncthreads();
    float p[4] = {0.f, 0.f, 0.f, 0.f};
    for (int j = 0; j < 256; j++){
      int f = hf*256 + j;
      float w = W2[f*128 + cc];
      #pragma unroll
      for (int ri = 0; ri < 4; ri++) p[ri] = fmaf(hbuf[ri*512 + f], w, p[ri]);
    }
    #pragma unroll
    for (int ri = 0; ri < 4; ri++) pt[ri*256 + tid] = p[ri];
    __syncthreads();
    float y[4];
    if (tid < 128){
      #pragma unroll
      for (int ri = 0; ri < 4; ri++){
        y[ri] = pt[ri*256 + tid] + pt[ri*256 + tid + 128] + b2v + xn[(row0+ri)*128 + tid];
        float s = wred_sum(y[ri]);
        float q = wred_sum(y[ri]*y[ri]);
        if (lane == 0){ redS[ri*2+wid] = s; redQ[ri*2+wid] = q; }
      }
    }
    __syncthreads();
    if (tid < 128){
      #pragma unroll
      for (int ri = 0; ri < 4; ri++){
        float S = redS[ri*2] + redS[ri*2+1];
        float Q = redQ[ri*2] + redQ[ri*2+1];
        float m = S * (1.f/128.f);
        float var = Q * (1.f/128.f) - m*m;
        xn[(row0+ri)*128 + tid] = (y[ri] - m) * rsqrtf(var + 1e-5f) * gv + bv;
      }
    }
    __syncthreads();
  }
}

// ---------------------------------------------------------------------------
// Kernel 5a: normalize measurement vectors. grid 1, block 128
// ---------------------------------------------------------------------------
__global__ void meas_norm_kernel(const float* mr, const float* mi, float* VMEAS)
{
  __shared__ float mn[128];
  int tid = threadIdx.x;
  float s = 0.f;
  for (int d = 0; d < 128; d++){
    float a = mr[tid*128 + d], b = mi[tid*128 + d];
    s += a*a + b*b;
  }
  mn[tid] = fmaxf(sqrtf(s), 1e-12f);
  __syncthreads();
  for (int i = tid; i < 16384; i += 128){
    int k = i >> 7;
    float inv = 1.f / mn[k];
    VMEAS[i]         = mr[i] * inv;
    VMEAS[16384 + i] = mi[i] * inv;
  }
}

// ---------------------------------------------------------------------------
// Kernel 5b: probs[k] = Re(v_k^dag rho v_k). grid (256 bt, 2 e-slabs), block 256
// ---------------------------------------------------------------------------
__global__ __launch_bounds__(256) void probs_kernel(const float* X, const float* VMEAS,
                                                    float* PROBS)
{
  __shared__ float sp[128];
  int bt = blockIdx.x, z = blockIdx.y, tid = threadIdx.x;
  const float* R  = X + (size_t)bt*16384;
  const float* I  = X + (size_t)(256+bt)*16384;
  const float* VR = VMEAS;
  const float* VI = VMEAS + 16384;
  if (tid < 128) sp[tid] = 0.f;
  __syncthreads();
  int kt = tid >> 3, et = tid & 7;
  int k0 = kt * 4;
  for (int pass = 0; pass < 2; pass++){
    int e0 = (z*2 + pass)*32 + et*4;
    float Cr[4][4] = {}, Ci[4][4] = {}, Dr[4][4] = {}, Di[4][4] = {};
    for (int d = 0; d < 128; d++){
      float vrk[4], vik[4], Rv[4], Iv[4];
      #pragma unroll
      for (int kk = 0; kk < 4; kk++){
        vrk[kk] = VR[(k0+kk)*128 + d];
        vik[kk] = VI[(k0+kk)*128 + d];
      }
      #pragma unroll
      for (int ee = 0; ee < 4; ee++){
        Rv[ee] = R[d*128 + e0 + ee];
        Iv[ee] = I[d*128 + e0 + ee];
      }
      #pragma unroll
      for (int kk = 0; kk < 4; kk++)
        #pragma unroll
        for (int ee = 0; ee < 4; ee++){
          Cr[kk][ee] = fmaf(vrk[kk], Rv[ee], Cr[kk][ee]);
          Ci[kk][ee] = fmaf(vik[kk], Rv[ee], Ci[kk][ee]);
          Dr[kk][ee] = fmaf(vrk[kk], Iv[ee], Dr[kk][ee]);
          Di[kk][ee] = fmaf(vik[kk], Iv[ee], Di[kk][ee]);
        }
    }
    #pragma unroll
    for (int kk = 0; kk < 4; kk++){
      float val = 0.f;
      #pragma unroll
      for (int ee = 0; ee < 4; ee++){
        float vre = VR[(k0+kk)*128 + e0 + ee];
        float vie = VI[(k0+kk)*128 + e0 + ee];
        val += vre * (Cr[kk][ee] + Di[kk][ee]) + vie * (Ci[kk][ee] - Dr[kk][ee]);
      }
      atomicAdd(&sp[k0+kk], val);
    }
  }
  __syncthreads();
  if (tid < 128) PROBS[(size_t)(z*256 + bt)*128 + tid] = sp[tid];
}

// ---------------------------------------------------------------------------
// Kernel 6: classifier head + log_softmax. grid 256 (bt), block 64
// ---------------------------------------------------------------------------
__global__ void head_kernel(const float* PROBS, const float* W1, const float* b1,
                            const float* W2, const float* b2, float* out)
{
  __shared__ float h[64];
  __shared__ float lg[7];
  __shared__ float mred[2];
  int bt = blockIdx.x, tid = threadIdx.x;
  float acc = b1[tid];
  for (int d = 0; d < 128; d++){
    float p = PROBS[bt*128 + d] + PROBS[(256+bt)*128 + d];
    acc = fmaf(p, W1[d*64 + tid], acc);
  }
  h[tid] = fmaxf(acc, 0.f);
  __syncthreads();
  if (tid < 7){
    float a = b2[tid];
    for (int j = 0; j < 64; j++) a = fmaf(h[j], W2[j*7 + tid], a);
    lg[tid] = a;
  }
  __syncthreads();
  if (tid == 0){
    float M = -1e30f;
    for (int c = 0; c < 7; c++) M = fmaxf(M, lg[c]);
    float S = 0.f;
    for (int c = 0; c < 7; c++) S += __expf(lg[c] - M);
    mred[0] = M; mred[1] = logf(S);
  }
  __syncthreads();
  if (tid < 7) out[bt*7 + tid] = lg[tid] - mred[0] - mred[1];
}

// ---------------------------------------------------------------------------
extern "C" void kernel_launch(void* const* d_in, const int* in_sizes, int n_in,
                              void* d_out, int out_size, void* d_ws, size_t ws_size,
                              hipStream_t stream)
{
  (void)in_sizes; (void)n_in; (void)out_size; (void)ws_size;
  const float* xt   = (const float*)d_in[0];
  const float* xv   = (const float*)d_in[1];
  const float* xa   = (const float*)d_in[2];
  const float* Wpt  = (const float*)d_in[3];
  const float* bpt  = (const float*)d_in[4];
  const float* Wpv  = (const float*)d_in[5];
  const float* bpv  = (const float*)d_in[6];
  const float* Wpa  = (const float*)d_in[7];
  const float* bpa  = (const float*)d_in[8];
  const float* l1   = (const float*)d_in[9];
  const float* l2   = (const float*)d_in[10];
  const float* Wl1  = (const float*)d_in[11];
  const float* bl1  = (const float*)d_in[12];
  const float* Wl2  = (const float*)d_in[13];
  const float* bl2  = (const float*)d_in[14];
  const float* pht  = (const float*)d_in[15];
  const float* phv  = (const float*)d_in[16];
  const float* pha  = (const float*)d_in[17];
  const float* Wqkv = (const float*)d_in[18];
  const float* bqkv = (const float*)d_in[19];
  const float* Wo   = (const float*)d_in[20];
  const float* bo   = (const float*)d_in[21];
  const float* g1   = (const float*)d_in[22];
  const float* b1   = (const float*)d_in[23];
  const float* W1   = (const float*)d_in[24];
  const float* bf1  = (const float*)d_in[25];
  const float* W2   = (const float*)d_in[26];
  const float* bf2  = (const float*)d_in[27];
  const float* g2   = (const float*)d_in[28];
  const float* b2   = (const float*)d_in[29];
  const float* mr   = (const float*)d_in[30];
  const float* mi   = (const float*)d_in[31];
  const float* fcW1 = (const float*)d_in[32];
  const float* fcb1 = (const float*)d_in[33];
  const float* fcW2 = (const float*)d_in[34];
  const float* fcb2 = (const float*)d_in[35];
  float* out = (float*)d_out;

  // workspace layout (bytes) -- total ~49.2 MB
  char* wsb = (char*)d_ws;
  float* X     = (float*)(wsb);                         // 512*16384 fp32 = 32 MB
  bf16*  ATTO  = (bf16*) (wsb + 33554432);              // 512*16384 bf16 = 16 MB
  float* PURE  = (float*)(wsb + 50331648);              // 256*768 fp32
  float* RNORM = (float*)(wsb + 51118080);              // 256*4
  float* LANGB = (float*)(wsb + 51122176);              // 512
  float* VMEAS = (float*)(wsb + 51124224);              // 2*16384 fp32
  float* PROBS = (float*)(wsb + 51255296);              // 2*256*128 fp32

  proj_kernel<<<256, 128, 0, stream>>>(xt, xv, xa, Wpt, bpt, Wpv, bpv, Wpa, bpa,
                                       pht, phv, pha, PURE, RNORM);
  lang_kernel<<<1, 128, 0, stream>>>(l1, l2, Wl1, bl1, Wl2, bl2, pht, LANGB);
  rho_kernel<<<256, 256, 0, stream>>>(PURE, RNORM, LANGB, X);

  for (int l = 0; l < 2; l++){
    attn_kernel<<<dim3(512, 4), 256, 0, stream>>>(X, Wqkv + (size_t)l*49152,
                                                  bqkv + (size_t)l*384, ATTO);
    proj_ln_kernel<<<512, 256, 0, stream>>>(ATTO, X, Wo + (size_t)l*16384,
                                            bo + (size_t)l*128, g1 + (size_t)l*128,
                                            b1 + (size_t)l*128);
    ffn_ln_kernel<<<512, 256, 0, stream>>>(X, W1 + (size_t)l*65536, bf1 + (size_t)l*512,
                                           W2 + (size_t)l*65536, bf2 + (size_t)l*128,
                                           g2 + (size_t)l*128, b2 + (size_t)l*128);
  }

  meas_norm_kernel<<<1, 128, 0, stream>>>(mr, mi, VMEAS);
  probs_kernel<<<dim3(256, 2), 256, 0, stream>>>(X, VMEAS, PROBS);
  head_kernel<<<256, 64, 0, stream>>>(PROBS, fcW1, fcb1, fcW2, fcb2, out);
}

// Round 4
// 2144.653 us; speedup vs baseline: 1.5874x; 1.5874x over previous
//
#include <hip/hip_runtime.h>
#include <hip/hip_bf16.h>

typedef __hip_bfloat16 bf16;
typedef short short8 __attribute__((ext_vector_type(8)));
typedef float f32x4 __attribute__((ext_vector_type(4)));

__device__ __forceinline__ float b2f(bf16 v){ return __bfloat162float(v); }

__device__ __forceinline__ short f2bs(float f){
  union { __hip_bfloat16 b; short s; } u; u.b = __float2bfloat16(f); return u.s;
}

__device__ __forceinline__ float wred_sum(float v){
  #pragma unroll
  for (int o = 32; o > 0; o >>= 1) v += __shfl_xor(v, o, 64);
  return v;
}

// ---------------------------------------------------------------------------
// Kernel 1: modality projections -> relu -> l2norm -> phase mul (pure states)
// grid 256 (bt), block 128
// ---------------------------------------------------------------------------
template<int DIMN>
__device__ void modality(const float* x, const float* W, const float* bia, const float* ph,
                         float* PURE, float* RNORM, int m, float* xs, float* red)
{
  int bt = blockIdx.x, tid = threadIdx.x;
  for (int i = tid; i < DIMN; i += 128) xs[i] = x[bt*DIMN + i];
  __syncthreads();
  float acc = bia[tid];
  for (int k = 0; k < DIMN; k++) acc = fmaf(xs[k], W[k*128 + tid], acc);
  float rep = fmaxf(acc, 0.f);
  float s = wred_sum(rep*rep);
  int wid = tid >> 6, lane = tid & 63;
  if (lane == 0) red[wid] = s;
  __syncthreads();
  float nrm = sqrtf(red[0] + red[1]);
  float amp = rep / fmaxf(nrm, 1e-12f);
  float p = ph[tid];
  PURE[bt*768 + m*128 + tid]       = amp * cosf(p);
  PURE[bt*768 + (3+m)*128 + tid]   = amp * sinf(p);
  if (tid == 0) RNORM[bt*4 + m] = nrm;
  __syncthreads();
}

__global__ void proj_kernel(const float* xt, const float* xv, const float* xa,
    const float* Wt, const float* bt_, const float* Wv, const float* bv,
    const float* Wa, const float* ba, const float* pht, const float* phv, const float* pha,
    float* PURE, float* RNORM)
{
  __shared__ float xs[600];
  __shared__ float red[2];
  modality<600>(xt, Wt, bt_, pht, PURE, RNORM, 0, xs, red);
  modality<342>(xv, Wv, bv,  phv, PURE, RNORM, 1, xs, red);
  modality<300>(xa, Wa, ba,  pha, PURE, RNORM, 2, xs, red);
}

// ---------------------------------------------------------------------------
// Kernel 2: language reps + Hadamard + entanglement (constant over b,t)
// grid 1, block 128.  LANGB: [0..127]=ent_r, [128..255]=ent_i, [256]=||lrep1||
// ---------------------------------------------------------------------------
__global__ void lang_kernel(const float* l1, const float* l2,
    const float* Wl1, const float* bl1, const float* Wl2, const float* bl2,
    const float* pht, float* LANGB)
{
  __shared__ float xs1[300], xs2[300];
  __shared__ float red[4];
  int tid = threadIdx.x;
  for (int i = tid; i < 300; i += 128){ xs1[i] = l1[i]; xs2[i] = l2[i]; }
  __syncthreads();
  float a1 = bl1[tid], a2 = bl2[tid];
  for (int k = 0; k < 300; k++){
    a1 = fmaf(xs1[k], Wl1[k*128 + tid], a1);
    a2 = fmaf(xs2[k], Wl2[k*128 + tid], a2);
  }
  a1 = fmaxf(a1, 0.f); a2 = fmaxf(a2, 0.f);
  int wid = tid >> 6, lane = tid & 63;
  float s1 = wred_sum(a1*a1), s2 = wred_sum(a2*a2);
  if (lane == 0){ red[wid] = s1; red[2+wid] = s2; }
  __syncthreads();
  float n1 = sqrtf(red[0] + red[1]);
  float n2 = sqrtf(red[2] + red[3]);
  float lamp1 = a1 / fmaxf(n1, 1e-12f);
  float lamp2 = a2 / fmaxf(n2, 1e-12f);
  float ph = pht[tid];
  float c = cosf(ph), s = sinf(ph);
  const float s2c = 0.70710678118654752f;
  float h1r = (lamp1*c + lamp1*s)*s2c, h1i = (lamp1*c - lamp1*s)*s2c;
  float h2r = (lamp2*c + lamp2*s)*s2c, h2i = (lamp2*c - lamp2*s)*s2c;
  float er = h1r*h2r - h1i*h2i;
  float ei = h1r*h2i + h1i*h2r;
  __syncthreads();
  float se = wred_sum(er*er + ei*ei);
  if (lane == 0) red[wid] = se;
  __syncthreads();
  float en = fmaxf(sqrtf(red[0] + red[1]), 1e-12f);
  LANGB[tid]       = er / en;
  LANGB[128 + tid] = ei / en;
  if (tid == 0) LANGB[256] = n1;
}

// ---------------------------------------------------------------------------
// Kernel 3: weighted sum of rank-1 density matrices -> X[0:256]=rho_r, X[256:512]=rho_i
// grid 256 (bt), block 256
// ---------------------------------------------------------------------------
__global__ __launch_bounds__(256) void rho_kernel(const float* PURE, const float* RNORM,
                                                  const float* LANGB, float* X)
{
  __shared__ float rv[4][128], iv[4][128], wsm[4];
  int bt = blockIdx.x, tid = threadIdx.x;
  for (int i = tid; i < 1024; i += 256){
    int d = i & 127;
    if (i < 768){ int m = i >> 7; float v = PURE[bt*768 + i];
                  if (m < 3) rv[m][d] = v; else iv[m-3][d] = v; }
    else if (i < 896) rv[3][d] = LANGB[d];
    else              iv[3][d] = LANGB[128 + d];
  }
  if (tid == 0){
    float n0 = RNORM[bt*4+0], n1 = RNORM[bt*4+1], n2 = RNORM[bt*4+2], n3 = LANGB[256];
    float mx = fmaxf(fmaxf(n0, n1), fmaxf(n2, n3));
    float e0 = __expf(n0-mx), e1 = __expf(n1-mx), e2 = __expf(n2-mx), e3 = __expf(n3-mx);
    float inv = 1.f / (e0+e1+e2+e3);
    wsm[0]=e0*inv; wsm[1]=e1*inv; wsm[2]=e2*inv; wsm[3]=e3*inv;
  }
  __syncthreads();
  float w0 = wsm[0], w1 = wsm[1], w2 = wsm[2], w3 = wsm[3];
  for (int idx = tid; idx < 16384; idx += 256){
    int d = idx >> 7, e = idx & 127;
    float rr = 0.f, ri = 0.f;
    {
      float rd=rv[0][d], re=rv[0][e], id=iv[0][d], ie=iv[0][e];
      rr = fmaf(w0, rd*re + id*ie, rr); ri = fmaf(w0, id*re - rd*ie, ri);
    }{
      float rd=rv[1][d], re=rv[1][e], id=iv[1][d], ie=iv[1][e];
      rr = fmaf(w1, rd*re + id*ie, rr); ri = fmaf(w1, id*re - rd*ie, ri);
    }{
      float rd=rv[2][d], re=rv[2][e], id=iv[2][d], ie=iv[2][e];
      rr = fmaf(w2, rd*re + id*ie, rr); ri = fmaf(w2, id*re - rd*ie, ri);
    }{
      float rd=rv[3][d], re=rv[3][e], id=iv[3][d], ie=iv[3][e];
      rr = fmaf(w3, rd*re + id*ie, rr); ri = fmaf(w3, id*re - rd*ie, ri);
    }
    X[(size_t)bt*16384 + idx]        = rr;
    X[(size_t)(256+bt)*16384 + idx]  = ri;
  }
}

// ---------------------------------------------------------------------------
// Kernel 4a: fused MHA per (sequence n, head h) via MFMA. grid (512,4), block 256.
// QKV GEMM (MFMA, bf16 in-flight) -> S=QK^T (MFMA) -> register softmax ->
// P via LDS (C-layout -> A-layout) -> PV (MFMA) -> ATTO bf16.
// LDS (42.5 KB): Vt[32][136] | Qs[128][40] / Ks[128][40] (overlaid by Ps[128][136])
// ---------------------------------------------------------------------------
__global__ __launch_bounds__(256) void attn_kernel(const float* __restrict__ X,
    const float* __restrict__ Wqkv, const float* __restrict__ bqkv,
    bf16* __restrict__ ATTO)
{
  __shared__ __align__(16) char lds_raw[43520];
  short* Vt = (short*)(lds_raw);           // [32][136]  (V transposed: Vt[hd][seq])
  short* Qs = (short*)(lds_raw + 8704);    // [128][40]
  short* Ks = (short*)(lds_raw + 18944);   // [128][40]
  short* Ps = (short*)(lds_raw + 8704);    // [128][136] overlaps Qs/Ks (dead by then)

  const int n = blockIdx.x, h = blockIdx.y;
  const int tid = threadIdx.x;
  const int wid = tid >> 6, lane = tid & 63;
  const int l15 = lane & 15, quad = lane >> 4;
  const float* xn = X + (size_t)n*16384;

  // ---- phase 1: QKV = X @ Wqkv + b (this head's 96 columns = 6 n-tiles) ----
  f32x4 acc[2][6];
  #pragma unroll
  for (int mi = 0; mi < 2; mi++)
    #pragma unroll
    for (int nt = 0; nt < 6; nt++){
      f32x4 z = {0.f, 0.f, 0.f, 0.f}; acc[mi][nt] = z;
    }

  #pragma unroll
  for (int ks = 0; ks < 4; ks++){
    short8 afr[2];
    #pragma unroll
    for (int mi = 0; mi < 2; mi++){
      int row = (wid*2 + mi)*16 + l15;
      const float* ap = xn + row*128 + ks*32 + quad*8;
      #pragma unroll
      for (int j = 0; j < 8; j++) afr[mi][j] = f2bs(ap[j]);
    }
    #pragma unroll
    for (int nt = 0; nt < 6; nt++){
      int col = (nt >> 1)*128 + h*32 + (nt & 1)*16 + l15;
      const float* bp = Wqkv + (size_t)(ks*32 + quad*8)*384 + col;
      short8 bfr;
      #pragma unroll
      for (int j = 0; j < 8; j++) bfr[j] = f2bs(bp[j*384]);
      #pragma unroll
      for (int mi = 0; mi < 2; mi++)
        acc[mi][nt] = __builtin_amdgcn_mfma_f32_16x16x32_bf16(afr[mi], bfr, acc[mi][nt], 0, 0, 0);
    }
  }
  // scatter C-layout (col=l15, row=quad*4+r) into LDS Q/K/Vt (bf16)
  #pragma unroll
  for (int nt = 0; nt < 6; nt++){
    int sec = nt >> 1;
    int cl = (nt & 1)*16 + l15;               // 0..31 within section
    float bias = bqkv[sec*128 + h*32 + cl];
    #pragma unroll
    for (int mi = 0; mi < 2; mi++){
      int rowb = (wid*2 + mi)*16 + quad*4;
      #pragma unroll
      for (int r = 0; r < 4; r++){
        float v = acc[mi][nt][r] + bias;
        int row = rowb + r;
        if (sec == 0)      Qs[row*40 + cl] = f2bs(v * 0.17677669529663687f);
        else if (sec == 1) Ks[row*40 + cl] = f2bs(v);
        else               Vt[cl*136 + row] = f2bs(v);
      }
    }
  }
  __syncthreads();

  // ---- phase 2: S = Q K^T (K-dim = 32 = exactly one MFMA k-step) ----
  f32x4 s[2][8];
  {
    short8 qf[2];
    #pragma unroll
    for (int mi = 0; mi < 2; mi++){
      int row = (wid*2 + mi)*16 + l15;
      qf[mi] = *(const short8*)(Qs + row*40 + quad*8);
    }
    #pragma unroll
    for (int nt = 0; nt < 8; nt++){
      int kr = nt*16 + l15;
      short8 kf = *(const short8*)(Ks + kr*40 + quad*8);
      #pragma unroll
      for (int mi = 0; mi < 2; mi++){
        f32x4 z = {0.f, 0.f, 0.f, 0.f};
        s[mi][nt] = __builtin_amdgcn_mfma_f32_16x16x32_bf16(qf[mi], kf, z, 0, 0, 0);
      }
    }
  }

  // ---- phase 3: softmax rows entirely in C-fragment registers ----
  #pragma unroll
  for (int mi = 0; mi < 2; mi++){
    #pragma unroll
    for (int r = 0; r < 4; r++){
      float m = -1e30f;
      #pragma unroll
      for (int nt = 0; nt < 8; nt++) m = fmaxf(m, s[mi][nt][r]);
      #pragma unroll
      for (int o = 1; o < 16; o <<= 1) m = fmaxf(m, __shfl_xor(m, o, 64));
      float sum = 0.f;
      #pragma unroll
      for (int nt = 0; nt < 8; nt++){
        float p = __expf(s[mi][nt][r] - m);
        s[mi][nt][r] = p; sum += p;
      }
      #pragma unroll
      for (int o = 1; o < 16; o <<= 1) sum += __shfl_xor(sum, o, 64);
      float inv = 1.f / sum;
      #pragma unroll
      for (int nt = 0; nt < 8; nt++) s[mi][nt][r] *= inv;
    }
  }
  __syncthreads();   // all waves done reading Qs/Ks -> safe to overlay with Ps

  // ---- phase 4: P -> LDS (C-layout -> row-major for A-frags) ----
  #pragma unroll
  for (int mi = 0; mi < 2; mi++){
    int rowb = (wid*2 + mi)*16 + quad*4;
    #pragma unroll
    for (int nt = 0; nt < 8; nt++){
      int col = nt*16 + l15;
      #pragma unroll
      for (int r = 0; r < 4; r++)
        Ps[(rowb + r)*136 + col] = f2bs(s[mi][nt][r]);
    }
  }
  __syncthreads();

  // ---- phase 5: O = P @ V ----
  f32x4 o_[2][2];
  #pragma unroll
  for (int mi = 0; mi < 2; mi++)
    #pragma unroll
    for (int n2 = 0; n2 < 2; n2++){
      f32x4 z = {0.f, 0.f, 0.f, 0.f}; o_[mi][n2] = z;
    }
  #pragma unroll
  for (int ks = 0; ks < 4; ks++){
    short8 pf[2];
    #pragma unroll
    for (int mi = 0; mi < 2; mi++){
      int row = (wid*2 + mi)*16 + l15;
      pf[mi] = *(const short8*)(Ps + row*136 + ks*32 + quad*8);
    }
    #pragma unroll
    for (int n2 = 0; n2 < 2; n2++){
      short8 vf = *(const short8*)(Vt + (n2*16 + l15)*136 + ks*32 + quad*8);
      #pragma unroll
      for (int mi = 0; mi < 2; mi++)
        o_[mi][n2] = __builtin_amdgcn_mfma_f32_16x16x32_bf16(pf[mi], vf, o_[mi][n2], 0, 0, 0);
    }
  }
  // ---- phase 6: write O head-slice to ATTO (bf16) ----
  bf16* on = ATTO + (size_t)n*16384;
  #pragma unroll
  for (int mi = 0; mi < 2; mi++){
    int rowb = (wid*2 + mi)*16 + quad*4;
    #pragma unroll
    for (int n2 = 0; n2 < 2; n2++){
      int col = h*32 + n2*16 + l15;
      #pragma unroll
      for (int r = 0; r < 4; r++)
        on[(rowb + r)*128 + col] = __float2bfloat16(o_[mi][n2][r]);
    }
  }
}

// ---------------------------------------------------------------------------
// Kernel 4b: X = LN(X + SRC@Wo + bo).  grid 512, block 256 (2 rows/iter)
// SRC is bf16 scratch.
// ---------------------------------------------------------------------------
__global__ __launch_bounds__(256) void proj_ln_kernel(const bf16* SRC, float* X,
    const float* Wo, const float* bo, const float* g, const float* bb)
{
  __shared__ float red[8];
  int n = blockIdx.x, tid = threadIdx.x;
  int half = tid >> 7, cc = tid & 127;
  int wid = tid >> 6, lane = tid & 63;
  const bf16* A = SRC + (size_t)n*16384;
  float* xn = X + (size_t)n*16384;
  float gv = g[cc], bv = bb[cc], bov = bo[cc];
  for (int rr = 0; rr < 64; rr++){
    int row = rr*2 + half;
    float acc = bov;
    for (int k = 0; k < 128; k++)
      acc = fmaf(b2f(A[row*128 + k]), Wo[k*128 + cc], acc);
    float y = acc + xn[row*128 + cc];
    float s = wred_sum(y), q = wred_sum(y*y);
    if (lane == 0){ red[wid*2] = s; red[wid*2+1] = q; }
    __syncthreads();
    float S = red[half*4+0] + red[half*4+2];
    float Q = red[half*4+1] + red[half*4+3];
    float m = S * (1.f/128.f);
    float var = Q * (1.f/128.f) - m*m;
    xn[row*128 + cc] = (y - m) * rsqrtf(var + 1e-5f) * gv + bv;
    __syncthreads();
  }
}

// ---------------------------------------------------------------------------
// Kernel 4c: X = LN(X + relu(X@W1+b1)@W2 + b2).  grid 512, block 256, 4 rows/iter
// ---------------------------------------------------------------------------
__global__ __launch_bounds__(256) void ffn_ln_kernel(float* X,
    const float* W1, const float* bf1, const float* W2, const float* bf2,
    const float* g, const float* bb)
{
  __shared__ float hbuf[4*512];
  __shared__ float pt[4*256];
  __shared__ float redS[8], redQ[8];
  int n = blockIdx.x, tid = threadIdx.x;
  int wid = tid >> 6, lane = tid & 63;
  float* xn = X + (size_t)n*16384;
  float b1a = bf1[tid], b1b = bf1[tid+256];
  int cc = tid & 127, hf = tid >> 7;
  float gv = g[cc], bv = bb[cc], b2v = bf2[cc];
  for (int it = 0; it < 32; it++){
    int row0 = it*4;
    float a[4][2];
    #pragma unroll
    for (int ri = 0; ri < 4; ri++){ a[ri][0] = b1a; a[ri][1] = b1b; }
    for (int k = 0; k < 128; k++){
      float w0 = W1[k*512 + tid];
      float w1 = W1[k*512 + tid + 256];
      #pragma unroll
      for (int ri = 0; ri < 4; ri++){
        float xv = xn[(row0+ri)*128 + k];
        a[ri][0] = fmaf(xv, w0, a[ri][0]);
        a[ri][1] = fmaf(xv, w1, a[ri][1]);
      }
    }
    #pragma unroll
    for (int ri = 0; ri < 4; ri++){
      hbuf[ri*512 + tid]       = fmaxf(a[ri][0], 0.f);
      hbuf[ri*512 + tid + 256] = fmaxf(a[ri][1], 0.f);
    }
    __syncthreads();
    float p[4] = {0.f, 0.f, 0.f, 0.f};
    for (int j = 0; j < 256; j++){
      int f = hf*256 + j;
      float w = W2[f*128 + cc];
      #pragma unroll
      for (int ri = 0; ri < 4; ri++) p[ri] = fmaf(hbuf[ri*512 + f], w, p[ri]);
    }
    #pragma unroll
    for (int ri = 0; ri < 4; ri++) pt[ri*256 + tid] = p[ri];
    __syncthreads();
    float y[4];
    if (tid < 128){
      #pragma unroll
      for (int ri = 0; ri < 4; ri++){
        y[ri] = pt[ri*256 + tid] + pt[ri*256 + tid + 128] + b2v + xn[(row0+ri)*128 + tid];
        float s = wred_sum(y[ri]);
        float q = wred_sum(y[ri]*y[ri]);
        if (lane == 0){ redS[ri*2+wid] = s; redQ[ri*2+wid] = q; }
      }
    }
    __syncthreads();
    if (tid < 128){
      #pragma unroll
      for (int ri = 0; ri < 4; ri++){
        float S = redS[ri*2] + redS[ri*2+1];
        float Q = redQ[ri*2] + redQ[ri*2+1];
        float m = S * (1.f/128.f);
        float var = Q * (1.f/128.f) - m*m;
        xn[(row0+ri)*128 + tid] = (y[ri] - m) * rsqrtf(var + 1e-5f) * gv + bv;
      }
    }
    __syncthreads();
  }
}

// ---------------------------------------------------------------------------
// Kernel 5a: normalize measurement vectors. grid 1, block 128
// ---------------------------------------------------------------------------
__global__ void meas_norm_kernel(const float* mr, const float* mi, float* VMEAS)
{
  __shared__ float mn[128];
  int tid = threadIdx.x;
  float s = 0.f;
  for (int d = 0; d < 128; d++){
    float a = mr[tid*128 + d], b = mi[tid*128 + d];
    s += a*a + b*b;
  }
  mn[tid] = fmaxf(sqrtf(s), 1e-12f);
  __syncthreads();
  for (int i = tid; i < 16384; i += 128){
    int k = i >> 7;
    float inv = 1.f / mn[k];
    VMEAS[i]         = mr[i] * inv;
    VMEAS[16384 + i] = mi[i] * inv;
  }
}

// ---------------------------------------------------------------------------
// Kernel 5b: probs[k] = Re(v_k^dag rho v_k). grid (256 bt, 2 e-slabs), block 256
// ---------------------------------------------------------------------------
__global__ __launch_bounds__(256) void probs_kernel(const float* X, const float* VMEAS,
                                                    float* PROBS)
{
  __shared__ float sp[128];
  int bt = blockIdx.x, z = blockIdx.y, tid = threadIdx.x;
  const float* R  = X + (size_t)bt*16384;
  const float* I  = X + (size_t)(256+bt)*16384;
  const float* VR = VMEAS;
  const float* VI = VMEAS + 16384;
  if (tid < 128) sp[tid] = 0.f;
  __syncthreads();
  int kt = tid >> 3, et = tid & 7;
  int k0 = kt * 4;
  for (int pass = 0; pass < 2; pass++){
    int e0 = (z*2 + pass)*32 + et*4;
    float Cr[4][4] = {}, Ci[4][4] = {}, Dr[4][4] = {}, Di[4][4] = {};
    for (int d = 0; d < 128; d++){
      float vrk[4], vik[4], Rv[4], Iv[4];
      #pragma unroll
      for (int kk = 0; kk < 4; kk++){
        vrk[kk] = VR[(k0+kk)*128 + d];
        vik[kk] = VI[(k0+kk)*128 + d];
      }
      #pragma unroll
      for (int ee = 0; ee < 4; ee++){
        Rv[ee] = R[d*128 + e0 + ee];
        Iv[ee] = I[d*128 + e0 + ee];
      }
      #pragma unroll
      for (int kk = 0; kk < 4; kk++)
        #pragma unroll
        for (int ee = 0; ee < 4; ee++){
          Cr[kk][ee] = fmaf(vrk[kk], Rv[ee], Cr[kk][ee]);
          Ci[kk][ee] = fmaf(vik[kk], Rv[ee], Ci[kk][ee]);
          Dr[kk][ee] = fmaf(vrk[kk], Iv[ee], Dr[kk][ee]);
          Di[kk][ee] = fmaf(vik[kk], Iv[ee], Di[kk][ee]);
        }
    }
    #pragma unroll
    for (int kk = 0; kk < 4; kk++){
      float val = 0.f;
      #pragma unroll
      for (int ee = 0; ee < 4; ee++){
        float vre = VR[(k0+kk)*128 + e0 + ee];
        float vie = VI[(k0+kk)*128 + e0 + ee];
        val += vre * (Cr[kk][ee] + Di[kk][ee]) + vie * (Ci[kk][ee] - Dr[kk][ee]);
      }
      atomicAdd(&sp[k0+kk], val);
    }
  }
  __syncthreads();
  if (tid < 128) PROBS[(size_t)(z*256 + bt)*128 + tid] = sp[tid];
}

// ---------------------------------------------------------------------------
// Kernel 6: classifier head + log_softmax. grid 256 (bt), block 64
// ---------------------------------------------------------------------------
__global__ void head_kernel(const float* PROBS, const float* W1, const float* b1,
                            const float* W2, const float* b2, float* out)
{
  __shared__ float h[64];
  __shared__ float lg[7];
  __shared__ float mred[2];
  int bt = blockIdx.x, tid = threadIdx.x;
  float acc = b1[tid];
  for (int d = 0; d < 128; d++){
    float p = PROBS[bt*128 + d] + PROBS[(256+bt)*128 + d];
    acc = fmaf(p, W1[d*64 + tid], acc);
  }
  h[tid] = fmaxf(acc, 0.f);
  __syncthreads();
  if (tid < 7){
    float a = b2[tid];
    for (int j = 0; j < 64; j++) a = fmaf(h[j], W2[j*7 + tid], a);
    lg[tid] = a;
  }
  __syncthreads();
  if (tid == 0){
    float M = -1e30f;
    for (int c = 0; c < 7; c++) M = fmaxf(M, lg[c]);
    float S = 0.f;
    for (int c = 0; c < 7; c++) S += __expf(lg[c] - M);
    mred[0] = M; mred[1] = logf(S);
  }
  __syncthreads();
  if (tid < 7) out[bt*7 + tid] = lg[tid] - mred[0] - mred[1];
}

// ---------------------------------------------------------------------------
extern "C" void kernel_launch(void* const* d_in, const int* in_sizes, int n_in,
                              void* d_out, int out_size, void* d_ws, size_t ws_size,
                              hipStream_t stream)
{
  (void)in_sizes; (void)n_in; (void)out_size; (void)ws_size;
  const float* xt   = (const float*)d_in[0];
  const float* xv   = (const float*)d_in[1];
  const float* xa   = (const float*)d_in[2];
  const float* Wpt  = (const float*)d_in[3];
  const float* bpt  = (const float*)d_in[4];
  const float* Wpv  = (const float*)d_in[5];
  const float* bpv  = (const float*)d_in[6];
  const float* Wpa  = (const float*)d_in[7];
  const float* bpa  = (const float*)d_in[8];
  const float* l1   = (const float*)d_in[9];
  const float* l2   = (const float*)d_in[10];
  const float* Wl1  = (const float*)d_in[11];
  const float* bl1  = (const float*)d_in[12];
  const float* Wl2  = (const float*)d_in[13];
  const float* bl2  = (const float*)d_in[14];
  const float* pht  = (const float*)d_in[15];
  const float* phv  = (const float*)d_in[16];
  const float* pha  = (const float*)d_in[17];
  const float* Wqkv = (const float*)d_in[18];
  const float* bqkv = (const float*)d_in[19];
  const float* Wo   = (const float*)d_in[20];
  const float* bo   = (const float*)d_in[21];
  const float* g1   = (const float*)d_in[22];
  const float* b1   = (const float*)d_in[23];
  const float* W1   = (const float*)d_in[24];
  const float* bf1  = (const float*)d_in[25];
  const float* W2   = (const float*)d_in[26];
  const float* bf2  = (const float*)d_in[27];
  const float* g2   = (const float*)d_in[28];
  const float* b2   = (const float*)d_in[29];
  const float* mr   = (const float*)d_in[30];
  const float* mi   = (const float*)d_in[31];
  const float* fcW1 = (const float*)d_in[32];
  const float* fcb1 = (const float*)d_in[33];
  const float* fcW2 = (const float*)d_in[34];
  const float* fcb2 = (const float*)d_in[35];
  float* out = (float*)d_out;

  // workspace layout (bytes) -- total ~49.2 MB
  char* wsb = (char*)d_ws;
  float* X     = (float*)(wsb);                         // 512*16384 fp32 = 32 MB
  bf16*  ATTO  = (bf16*) (wsb + 33554432);              // 512*16384 bf16 = 16 MB
  float* PURE  = (float*)(wsb + 50331648);              // 256*768 fp32
  float* RNORM = (float*)(wsb + 51118080);              // 256*4
  float* LANGB = (float*)(wsb + 51122176);              // 512
  float* VMEAS = (float*)(wsb + 51124224);              // 2*16384 fp32
  float* PROBS = (float*)(wsb + 51255296);              // 2*256*128 fp32

  proj_kernel<<<256, 128, 0, stream>>>(xt, xv, xa, Wpt, bpt, Wpv, bpv, Wpa, bpa,
                                       pht, phv, pha, PURE, RNORM);
  lang_kernel<<<1, 128, 0, stream>>>(l1, l2, Wl1, bl1, Wl2, bl2, pht, LANGB);
  rho_kernel<<<256, 256, 0, stream>>>(PURE, RNORM, LANGB, X);

  for (int l = 0; l < 2; l++){
    attn_kernel<<<dim3(512, 4), 256, 0, stream>>>(X, Wqkv + (size_t)l*49152,
                                                  bqkv + (size_t)l*384, ATTO);
    proj_ln_kernel<<<512, 256, 0, stream>>>(ATTO, X, Wo + (size_t)l*16384,
                                            bo + (size_t)l*128, g1 + (size_t)l*128,
                                            b1 + (size_t)l*128);
    ffn_ln_kernel<<<512, 256, 0, stream>>>(X, W1 + (size_t)l*65536, bf1 + (size_t)l*512,
                                           W2 + (size_t)l*65536, bf2 + (size_t)l*128,
                                           g2 + (size_t)l*128, b2 + (size_t)l*128);
  }

  meas_norm_kernel<<<1, 128, 0, stream>>>(mr, mi, VMEAS);
  probs_kernel<<<dim3(256, 2), 256, 0, stream>>>(X, VMEAS, PROBS);
  head_kernel<<<256, 64, 0, stream>>>(PROBS, fcW1, fcb1, fcW2, fcb2, out);
}

// Round 7
// 898.778 us; speedup vs baseline: 3.7877x; 2.3862x over previous
//
#include <hip/hip_runtime.h>
#include <hip/hip_bf16.h>

typedef __hip_bfloat16 bf16;
typedef short short8 __attribute__((ext_vector_type(8)));
typedef float f32x4 __attribute__((ext_vector_type(4)));

__device__ __forceinline__ float b2f(bf16 v){ return __bfloat162float(v); }

__device__ __forceinline__ short f2bs(float f){
  union { __hip_bfloat16 b; short s; } u; u.b = __float2bfloat16(f); return u.s;
}
__device__ __forceinline__ float bs2f(short s){
  union { short s; __hip_bfloat16 b; } u; u.s = s; return __bfloat162float(u.b);
}

__device__ __forceinline__ float wred_sum(float v){
  #pragma unroll
  for (int o = 32; o > 0; o >>= 1) v += __shfl_xor(v, o, 64);
  return v;
}

// ---------------------------------------------------------------------------
// Kernel 0a: weight transpose + bf16.  in [K][N] fp32 -> out [N][K] bf16
// ---------------------------------------------------------------------------
__global__ void wT_kernel(const float* __restrict__ in, short* __restrict__ out,
                          int K, int N)
{
  int base = blockIdx.y * K * N;
  int i0 = blockIdx.x * 1024;
  #pragma unroll
  for (int t = 0; t < 4; t++){
    int i = i0 + t*256 + threadIdx.x;
    if (i < K*N){
      int nn = i / K, kk = i - nn*K;
      out[base + i] = f2bs(in[base + kk*N + nn]);
    }
  }
}

// ---------------------------------------------------------------------------
// Kernel 0b: weight transpose + hi/lo bf16 split.  in [K][N] -> hi/lo [N][K]
// ---------------------------------------------------------------------------
__global__ void wT2_kernel(const float* __restrict__ in, short* __restrict__ ohi,
                           short* __restrict__ olo, int K, int N)
{
  int base = blockIdx.y * K * N;
  int i0 = blockIdx.x * 1024;
  #pragma unroll
  for (int t = 0; t < 4; t++){
    int i = i0 + t*256 + threadIdx.x;
    if (i < K*N){
      int nn = i / K, kk = i - nn*K;
      float w = in[base + kk*N + nn];
      short hi = f2bs(w);
      ohi[base + i] = hi;
      olo[base + i] = f2bs(w - bs2f(hi));
    }
  }
}

// ---------------------------------------------------------------------------
// Kernel 1: modality projections -> relu -> l2norm -> phase mul (pure states)
// ---------------------------------------------------------------------------
template<int DIMN>
__device__ void modality(const float* x, const float* W, const float* bia, const float* ph,
                         float* PURE, float* RNORM, int m, float* xs, float* red)
{
  int bt = blockIdx.x, tid = threadIdx.x;
  for (int i = tid; i < DIMN; i += 128) xs[i] = x[bt*DIMN + i];
  __syncthreads();
  float acc = bia[tid];
  for (int k = 0; k < DIMN; k++) acc = fmaf(xs[k], W[k*128 + tid], acc);
  float rep = fmaxf(acc, 0.f);
  float s = wred_sum(rep*rep);
  int wid = tid >> 6, lane = tid & 63;
  if (lane == 0) red[wid] = s;
  __syncthreads();
  float nrm = sqrtf(red[0] + red[1]);
  float amp = rep / fmaxf(nrm, 1e-12f);
  float p = ph[tid];
  PURE[bt*768 + m*128 + tid]       = amp * cosf(p);
  PURE[bt*768 + (3+m)*128 + tid]   = amp * sinf(p);
  if (tid == 0) RNORM[bt*4 + m] = nrm;
  __syncthreads();
}

__global__ void proj_kernel(const float* xt, const float* xv, const float* xa,
    const float* Wt, const float* bt_, const float* Wv, const float* bv,
    const float* Wa, const float* ba, const float* pht, const float* phv, const float* pha,
    float* PURE, float* RNORM)
{
  __shared__ float xs[600];
  __shared__ float red[2];
  modality<600>(xt, Wt, bt_, pht, PURE, RNORM, 0, xs, red);
  modality<342>(xv, Wv, bv,  phv, PURE, RNORM, 1, xs, red);
  modality<300>(xa, Wa, ba,  pha, PURE, RNORM, 2, xs, red);
}

// ---------------------------------------------------------------------------
// Kernel 2: language reps + Hadamard + entanglement
// ---------------------------------------------------------------------------
__global__ void lang_kernel(const float* l1, const float* l2,
    const float* Wl1, const float* bl1, const float* Wl2, const float* bl2,
    const float* pht, float* LANGB)
{
  __shared__ float xs1[300], xs2[300];
  __shared__ float red[4];
  int tid = threadIdx.x;
  for (int i = tid; i < 300; i += 128){ xs1[i] = l1[i]; xs2[i] = l2[i]; }
  __syncthreads();
  float a1 = bl1[tid], a2 = bl2[tid];
  for (int k = 0; k < 300; k++){
    a1 = fmaf(xs1[k], Wl1[k*128 + tid], a1);
    a2 = fmaf(xs2[k], Wl2[k*128 + tid], a2);
  }
  a1 = fmaxf(a1, 0.f); a2 = fmaxf(a2, 0.f);
  int wid = tid >> 6, lane = tid & 63;
  float s1 = wred_sum(a1*a1), s2 = wred_sum(a2*a2);
  if (lane == 0){ red[wid] = s1; red[2+wid] = s2; }
  __syncthreads();
  float n1 = sqrtf(red[0] + red[1]);
  float n2 = sqrtf(red[2] + red[3]);
  float lamp1 = a1 / fmaxf(n1, 1e-12f);
  float lamp2 = a2 / fmaxf(n2, 1e-12f);
  float ph = pht[tid];
  float c = cosf(ph), s = sinf(ph);
  const float s2c = 0.70710678118654752f;
  float h1r = (lamp1*c + lamp1*s)*s2c, h1i = (lamp1*c - lamp1*s)*s2c;
  float h2r = (lamp2*c + lamp2*s)*s2c, h2i = (lamp2*c - lamp2*s)*s2c;
  float er = h1r*h2r - h1i*h2i;
  float ei = h1r*h2i + h1i*h2r;
  __syncthreads();
  float se = wred_sum(er*er + ei*ei);
  if (lane == 0) red[wid] = se;
  __syncthreads();
  float en = fmaxf(sqrtf(red[0] + red[1]), 1e-12f);
  LANGB[tid]       = er / en;
  LANGB[128 + tid] = ei / en;
  if (tid == 0) LANGB[256] = n1;
}

// ---------------------------------------------------------------------------
// Kernel 3: weighted sum of rank-1 density matrices
// ---------------------------------------------------------------------------
__global__ __launch_bounds__(256) void rho_kernel(const float* PURE, const float* RNORM,
                                                  const float* LANGB, float* X)
{
  __shared__ float rv[4][128], iv[4][128], wsm[4];
  int bt = blockIdx.x, tid = threadIdx.x;
  for (int i = tid; i < 1024; i += 256){
    int d = i & 127;
    if (i < 768){ int m = i >> 7; float v = PURE[bt*768 + i];
                  if (m < 3) rv[m][d] = v; else iv[m-3][d] = v; }
    else if (i < 896) rv[3][d] = LANGB[d];
    else              iv[3][d] = LANGB[128 + d];
  }
  if (tid == 0){
    float n0 = RNORM[bt*4+0], n1 = RNORM[bt*4+1], n2 = RNORM[bt*4+2], n3 = LANGB[256];
    float mx = fmaxf(fmaxf(n0, n1), fmaxf(n2, n3));
    float e0 = __expf(n0-mx), e1 = __expf(n1-mx), e2 = __expf(n2-mx), e3 = __expf(n3-mx);
    float inv = 1.f / (e0+e1+e2+e3);
    wsm[0]=e0*inv; wsm[1]=e1*inv; wsm[2]=e2*inv; wsm[3]=e3*inv;
  }
  __syncthreads();
  float w0 = wsm[0], w1 = wsm[1], w2 = wsm[2], w3 = wsm[3];
  for (int idx = tid; idx < 16384; idx += 256){
    int d = idx >> 7, e = idx & 127;
    float rr = 0.f, ri = 0.f;
    {
      float rd=rv[0][d], re=rv[0][e], id=iv[0][d], ie=iv[0][e];
      rr = fmaf(w0, rd*re + id*ie, rr); ri = fmaf(w0, id*re - rd*ie, ri);
    }{
      float rd=rv[1][d], re=rv[1][e], id=iv[1][d], ie=iv[1][e];
      rr = fmaf(w1, rd*re + id*ie, rr); ri = fmaf(w1, id*re - rd*ie, ri);
    }{
      float rd=rv[2][d], re=rv[2][e], id=iv[2][d], ie=iv[2][e];
      rr = fmaf(w2, rd*re + id*ie, rr); ri = fmaf(w2, id*re - rd*ie, ri);
    }{
      float rd=rv[3][d], re=rv[3][e], id=iv[3][d], ie=iv[3][e];
      rr = fmaf(w3, rd*re + id*ie, rr); ri = fmaf(w3, id*re - rd*ie, ri);
    }
    X[(size_t)bt*16384 + idx]        = rr;
    X[(size_t)(256+bt)*16384 + idx]  = ri;
  }
}

// ---------------------------------------------------------------------------
// Kernel 4a: fused MHA per (sequence n, head h) via MFMA. grid (512,4), block 256.
// ---------------------------------------------------------------------------
__global__ __launch_bounds__(256) void attn_kernel(const float* __restrict__ X,
    const short* __restrict__ WqkvT, const float* __restrict__ bqkv,
    bf16* __restrict__ ATTO)
{
  __shared__ __align__(16) char lds_raw[43520];
  short* Vt = (short*)(lds_raw);           // [32][136]
  short* Qs = (short*)(lds_raw + 8704);    // [128][40]
  short* Ks = (short*)(lds_raw + 18944);   // [128][40]
  short* Ps = (short*)(lds_raw + 8704);    // [128][136] overlays Qs/Ks

  const int n = blockIdx.x, h = blockIdx.y;
  const int tid = threadIdx.x;
  const int wid = tid >> 6, lane = tid & 63;
  const int l15 = lane & 15, quad = lane >> 4;
  const float* xn = X + (size_t)n*16384;

  f32x4 acc[2][6];
  #pragma unroll
  for (int mi = 0; mi < 2; mi++)
    #pragma unroll
    for (int nt = 0; nt < 6; nt++){
      f32x4 z = {0.f, 0.f, 0.f, 0.f}; acc[mi][nt] = z;
    }

  #pragma unroll
  for (int ks = 0; ks < 4; ks++){
    short8 afr[2];
    #pragma unroll
    for (int mi = 0; mi < 2; mi++){
      int row = (wid*2 + mi)*16 + l15;
      const float* ap = xn + row*128 + ks*32 + quad*8;
      #pragma unroll
      for (int j = 0; j < 8; j++) afr[mi][j] = f2bs(ap[j]);
    }
    #pragma unroll
    for (int nt = 0; nt < 6; nt++){
      int col = (nt >> 1)*128 + h*32 + (nt & 1)*16 + l15;
      short8 bfr = *(const short8*)(WqkvT + (size_t)col*128 + ks*32 + quad*8);
      #pragma unroll
      for (int mi = 0; mi < 2; mi++)
        acc[mi][nt] = __builtin_amdgcn_mfma_f32_16x16x32_bf16(afr[mi], bfr, acc[mi][nt], 0, 0, 0);
    }
  }
  #pragma unroll
  for (int nt = 0; nt < 6; nt++){
    int sec = nt >> 1;
    int cl = (nt & 1)*16 + l15;
    float bias = bqkv[sec*128 + h*32 + cl];
    #pragma unroll
    for (int mi = 0; mi < 2; mi++){
      int rowb = (wid*2 + mi)*16 + quad*4;
      #pragma unroll
      for (int r = 0; r < 4; r++){
        float v = acc[mi][nt][r] + bias;
        int row = rowb + r;
        if (sec == 0)      Qs[row*40 + cl] = f2bs(v * 0.17677669529663687f);
        else if (sec == 1) Ks[row*40 + cl] = f2bs(v);
        else               Vt[cl*136 + row] = f2bs(v);
      }
    }
  }
  __syncthreads();

  f32x4 s[2][8];
  {
    short8 qf[2];
    #pragma unroll
    for (int mi = 0; mi < 2; mi++){
      int row = (wid*2 + mi)*16 + l15;
      qf[mi] = *(const short8*)(Qs + row*40 + quad*8);
    }
    #pragma unroll
    for (int nt = 0; nt < 8; nt++){
      int kr = nt*16 + l15;
      short8 kf = *(const short8*)(Ks + kr*40 + quad*8);
      #pragma unroll
      for (int mi = 0; mi < 2; mi++){
        f32x4 z = {0.f, 0.f, 0.f, 0.f};
        s[mi][nt] = __builtin_amdgcn_mfma_f32_16x16x32_bf16(qf[mi], kf, z, 0, 0, 0);
      }
    }
  }

  #pragma unroll
  for (int mi = 0; mi < 2; mi++){
    #pragma unroll
    for (int r = 0; r < 4; r++){
      float m = -1e30f;
      #pragma unroll
      for (int nt = 0; nt < 8; nt++) m = fmaxf(m, s[mi][nt][r]);
      #pragma unroll
      for (int o = 1; o < 16; o <<= 1) m = fmaxf(m, __shfl_xor(m, o, 64));
      float sum = 0.f;
      #pragma unroll
      for (int nt = 0; nt < 8; nt++){
        float p = __expf(s[mi][nt][r] - m);
        s[mi][nt][r] = p; sum += p;
      }
      #pragma unroll
      for (int o = 1; o < 16; o <<= 1) sum += __shfl_xor(sum, o, 64);
      float inv = 1.f / sum;
      #pragma unroll
      for (int nt = 0; nt < 8; nt++) s[mi][nt][r] *= inv;
    }
  }
  __syncthreads();

  #pragma unroll
  for (int mi = 0; mi < 2; mi++){
    int rowb = (wid*2 + mi)*16 + quad*4;
    #pragma unroll
    for (int nt = 0; nt < 8; nt++){
      int col = nt*16 + l15;
      #pragma unroll
      for (int r = 0; r < 4; r++)
        Ps[(rowb + r)*136 + col] = f2bs(s[mi][nt][r]);
    }
  }
  __syncthreads();

  f32x4 o_[2][2];
  #pragma unroll
  for (int mi = 0; mi < 2; mi++)
    #pragma unroll
    for (int n2 = 0; n2 < 2; n2++){
      f32x4 z = {0.f, 0.f, 0.f, 0.f}; o_[mi][n2] = z;
    }
  #pragma unroll
  for (int ks = 0; ks < 4; ks++){
    short8 pf[2];
    #pragma unroll
    for (int mi = 0; mi < 2; mi++){
      int row = (wid*2 + mi)*16 + l15;
      pf[mi] = *(const short8*)(Ps + row*136 + ks*32 + quad*8);
    }
    #pragma unroll
    for (int n2 = 0; n2 < 2; n2++){
      short8 vf = *(const short8*)(Vt + (n2*16 + l15)*136 + ks*32 + quad*8);
      #pragma unroll
      for (int mi = 0; mi < 2; mi++)
        o_[mi][n2] = __builtin_amdgcn_mfma_f32_16x16x32_bf16(pf[mi], vf, o_[mi][n2], 0, 0, 0);
    }
  }
  bf16* on = ATTO + (size_t)n*16384;
  #pragma unroll
  for (int mi = 0; mi < 2; mi++){
    int rowb = (wid*2 + mi)*16 + quad*4;
    #pragma unroll
    for (int n2 = 0; n2 < 2; n2++){
      int col = h*32 + n2*16 + l15;
      #pragma unroll
      for (int r = 0; r < 4; r++)
        on[(rowb + r)*128 + col] = __float2bfloat16(o_[mi][n2][r]);
    }
  }
}

// ---------------------------------------------------------------------------
// Kernel 4b: X = LN(X + SRC@Wo + bo), MFMA 2-term (Wo hi/lo split).
// ---------------------------------------------------------------------------
__global__ __launch_bounds__(256) void proj_ln_kernel(const bf16* __restrict__ SRC,
    float* __restrict__ X, const short* __restrict__ Wh, const short* __restrict__ Wl,
    const float* __restrict__ bo, const float* __restrict__ g,
    const float* __restrict__ bb)
{
  const int n = blockIdx.x, tid = threadIdx.x;
  const int wid = tid >> 6, lane = tid & 63;
  const int l15 = lane & 15, quad = lane >> 4;
  const short* an = (const short*)SRC + (size_t)n*16384;
  float* xn = X + (size_t)n*16384;

  f32x4 Y[2][8];
  #pragma unroll
  for (int mi = 0; mi < 2; mi++)
    #pragma unroll
    for (int nt = 0; nt < 8; nt++){ f32x4 z = {0.f,0.f,0.f,0.f}; Y[mi][nt] = z; }

  #pragma unroll
  for (int ks = 0; ks < 4; ks++){
    short8 af[2];
    #pragma unroll
    for (int mi = 0; mi < 2; mi++){
      int row = (wid*2 + mi)*16 + l15;
      af[mi] = *(const short8*)(an + row*128 + ks*32 + quad*8);
    }
    #pragma unroll
    for (int nt = 0; nt < 8; nt++){
      int coln = nt*16 + l15;
      short8 bh = *(const short8*)(Wh + coln*128 + ks*32 + quad*8);
      short8 bl = *(const short8*)(Wl + coln*128 + ks*32 + quad*8);
      #pragma unroll
      for (int mi = 0; mi < 2; mi++){
        Y[mi][nt] = __builtin_amdgcn_mfma_f32_16x16x32_bf16(af[mi], bh, Y[mi][nt], 0, 0, 0);
        Y[mi][nt] = __builtin_amdgcn_mfma_f32_16x16x32_bf16(af[mi], bl, Y[mi][nt], 0, 0, 0);
      }
    }
  }

  float bov[8], gv[8], bbv[8];
  #pragma unroll
  for (int nt = 0; nt < 8; nt++){
    int col = nt*16 + l15;
    bov[nt] = bo[col]; gv[nt] = g[col]; bbv[nt] = bb[col];
  }

  #pragma unroll
  for (int mi = 0; mi < 2; mi++){
    #pragma unroll
    for (int r = 0; r < 4; r++){
      int row = (wid*2 + mi)*16 + quad*4 + r;
      float yv[8]; float S = 0.f, Q = 0.f;
      #pragma unroll
      for (int nt = 0; nt < 8; nt++){
        int col = nt*16 + l15;
        float y = Y[mi][nt][r] + bov[nt] + xn[row*128 + col];
        yv[nt] = y; S += y; Q += y*y;
      }
      #pragma unroll
      for (int o = 1; o < 16; o <<= 1){ S += __shfl_xor(S, o, 64); Q += __shfl_xor(Q, o, 64); }
      float m = S * (1.f/128.f);
      float var = Q * (1.f/128.f) - m*m;
      float inv = rsqrtf(var + 1e-5f);
      #pragma unroll
      for (int nt = 0; nt < 8; nt++){
        int col = nt*16 + l15;
        xn[row*128 + col] = (yv[nt] - m) * inv * gv[nt] + bbv[nt];
      }
    }
  }
}

// ---------------------------------------------------------------------------
// Kernel 4c: X = LN(X + relu(X@W1+b1)@W2 + b2), MFMA 3-term hi/lo split.
// ---------------------------------------------------------------------------
__global__ __launch_bounds__(256) void ffn_ln_kernel(float* __restrict__ X,
    const short* __restrict__ W1h, const short* __restrict__ W1l,
    const float* __restrict__ bf1,
    const short* __restrict__ W2h, const short* __restrict__ W2l,
    const float* __restrict__ bf2,
    const float* __restrict__ g, const float* __restrict__ bb)
{
  __shared__ __align__(16) short Hh[128*136];
  __shared__ __align__(16) short Hl[128*136];
  const int n = blockIdx.x, tid = threadIdx.x;
  const int wid = tid >> 6, lane = tid & 63;
  const int l15 = lane & 15, quad = lane >> 4;
  float* xn = X + (size_t)n*16384;

  f32x4 Y[2][8];
  #pragma unroll
  for (int mi = 0; mi < 2; mi++)
    #pragma unroll
    for (int nt = 0; nt < 8; nt++){ f32x4 z = {0.f,0.f,0.f,0.f}; Y[mi][nt] = z; }

  for (int c = 0; c < 4; c++){
    f32x4 Hc[2][8];
    #pragma unroll
    for (int mi = 0; mi < 2; mi++)
      #pragma unroll
      for (int nt = 0; nt < 8; nt++){ f32x4 z = {0.f,0.f,0.f,0.f}; Hc[mi][nt] = z; }
    #pragma unroll
    for (int ks = 0; ks < 4; ks++){
      short8 ah[2], al[2];
      #pragma unroll
      for (int mi = 0; mi < 2; mi++){
        int row = (wid*2 + mi)*16 + l15;
        const float* ap = xn + row*128 + ks*32 + quad*8;
        #pragma unroll
        for (int j = 0; j < 8; j++){
          float v = ap[j];
          short hi = f2bs(v);
          ah[mi][j] = hi;
          al[mi][j] = f2bs(v - bs2f(hi));
        }
      }
      #pragma unroll
      for (int nt = 0; nt < 8; nt++){
        int colg = c*128 + nt*16 + l15;
        short8 bh = *(const short8*)(W1h + colg*128 + ks*32 + quad*8);
        short8 bl = *(const short8*)(W1l + colg*128 + ks*32 + quad*8);
        #pragma unroll
        for (int mi = 0; mi < 2; mi++){
          Hc[mi][nt] = __builtin_amdgcn_mfma_f32_16x16x32_bf16(ah[mi], bh, Hc[mi][nt], 0, 0, 0);
          Hc[mi][nt] = __builtin_amdgcn_mfma_f32_16x16x32_bf16(ah[mi], bl, Hc[mi][nt], 0, 0, 0);
          Hc[mi][nt] = __builtin_amdgcn_mfma_f32_16x16x32_bf16(al[mi], bh, Hc[mi][nt], 0, 0, 0);
        }
      }
    }
    __syncthreads();   // previous chunk's GEMM2 reads of Hh/Hl complete
    #pragma unroll
    for (int nt = 0; nt < 8; nt++){
      int col = nt*16 + l15;
      float b1v = bf1[c*128 + col];
      #pragma unroll
      for (int mi = 0; mi < 2; mi++){
        int rowb = (wid*2 + mi)*16 + quad*4;
        #pragma unroll
        for (int r = 0; r < 4; r++){
          float h = fmaxf(Hc[mi][nt][r] + b1v, 0.f);
          short hi = f2bs(h);
          Hh[(rowb + r)*136 + col] = hi;
          Hl[(rowb + r)*136 + col] = f2bs(h - bs2f(hi));
        }
      }
    }
    __syncthreads();
    #pragma unroll
    for (int ks = 0; ks < 4; ks++){
      short8 ph[2], pl[2];
      #pragma unroll
      for (int mi = 0; mi < 2; mi++){
        int row = (wid*2 + mi)*16 + l15;
        ph[mi] = *(const short8*)(Hh + row*136 + ks*32 + quad*8);
        pl[mi] = *(const short8*)(Hl + row*136 + ks*32 + quad*8);
      }
      #pragma unroll
      for (int nt = 0; nt < 8; nt++){
        int coln = nt*16 + l15;
        short8 bh = *(const short8*)(W2h + coln*512 + c*128 + ks*32 + quad*8);
        short8 bl = *(const short8*)(W2l + coln*512 + c*128 + ks*32 + quad*8);
        #pragma unroll
        for (int mi = 0; mi < 2; mi++){
          Y[mi][nt] = __builtin_amdgcn_mfma_f32_16x16x32_bf16(ph[mi], bh, Y[mi][nt], 0, 0, 0);
          Y[mi][nt] = __builtin_amdgcn_mfma_f32_16x16x32_bf16(ph[mi], bl, Y[mi][nt], 0, 0, 0);
          Y[mi][nt] = __builtin_amdgcn_mfma_f32_16x16x32_bf16(pl[mi], bh, Y[mi][nt], 0, 0, 0);
        }
      }
    }
  }

  float b2v[8], gv[8], bbv[8];
  #pragma unroll
  for (int nt = 0; nt < 8; nt++){
    int col = nt*16 + l15;
    b2v[nt] = bf2[col]; gv[nt] = g[col]; bbv[nt] = bb[col];
  }

  #pragma unroll
  for (int mi = 0; mi < 2; mi++){
    #pragma unroll
    for (int r = 0; r < 4; r++){
      int row = (wid*2 + mi)*16 + quad*4 + r;
      float yv[8]; float S = 0.f, Q = 0.f;
      #pragma unroll
      for (int nt = 0; nt < 8; nt++){
        int col = nt*16 + l15;
        float y = Y[mi][nt][r] + b2v[nt] + xn[row*128 + col];
        yv[nt] = y; S += y; Q += y*y;
      }
      #pragma unroll
      for (int o = 1; o < 16; o <<= 1){ S += __shfl_xor(S, o, 64); Q += __shfl_xor(Q, o, 64); }
      float m = S * (1.f/128.f);
      float var = Q * (1.f/128.f) - m*m;
      float inv = rsqrtf(var + 1e-5f);
      #pragma unroll
      for (int nt = 0; nt < 8; nt++){
        int col = nt*16 + l15;
        xn[row*128 + col] = (yv[nt] - m) * inv * gv[nt] + bbv[nt];
      }
    }
  }
}

// ---------------------------------------------------------------------------
// Kernel 5a: normalize measurement vectors. grid 1, block 128
// ---------------------------------------------------------------------------
__global__ void meas_norm_kernel(const float* mr, const float* mi, float* VMEAS)
{
  __shared__ float mn[128];
  int tid = threadIdx.x;
  float s = 0.f;
  for (int d = 0; d < 128; d++){
    float a = mr[tid*128 + d], b = mi[tid*128 + d];
    s += a*a + b*b;
  }
  mn[tid] = fmaxf(sqrtf(s), 1e-12f);
  __syncthreads();
  for (int i = tid; i < 16384; i += 128){
    int k = i >> 7;
    float inv = 1.f / mn[k];
    VMEAS[i]         = mr[i] * inv;
    VMEAS[16384 + i] = mi[i] * inv;
  }
}

// ---------------------------------------------------------------------------
// Kernel 5b: probs[k] = Re(v_k^dag rho v_k). grid (256 bt, 2 e-slabs), block 256
// ---------------------------------------------------------------------------
__global__ __launch_bounds__(256) void probs_kernel(const float* X, const float* VMEAS,
                                                    float* PROBS)
{
  __shared__ float sp[128];
  int bt = blockIdx.x, z = blockIdx.y, tid = threadIdx.x;
  const float* R  = X + (size_t)bt*16384;
  const float* I  = X + (size_t)(256+bt)*16384;
  const float* VR = VMEAS;
  const float* VI = VMEAS + 16384;
  if (tid < 128) sp[tid] = 0.f;
  __syncthreads();
  int kt = tid >> 3, et = tid & 7;
  int k0 = kt * 4;
  for (int pass = 0; pass < 2; pass++){
    int e0 = (z*2 + pass)*32 + et*4;
    float Cr[4][4] = {}, Ci[4][4] = {}, Dr[4][4] = {}, Di[4][4] = {};
    for (int d = 0; d < 128; d++){
      float vrk[4], vik[4], Rv[4], Iv[4];
      #pragma unroll
      for (int kk = 0; kk < 4; kk++){
        vrk[kk] = VR[(k0+kk)*128 + d];
        vik[kk] = VI[(k0+kk)*128 + d];
      }
      #pragma unroll
      for (int ee = 0; ee < 4; ee++){
        Rv[ee] = R[d*128 + e0 + ee];
        Iv[ee] = I[d*128 + e0 + ee];
      }
      #pragma unroll
      for (int kk = 0; kk < 4; kk++)
        #pragma unroll
        for (int ee = 0; ee < 4; ee++){
          Cr[kk][ee] = fmaf(vrk[kk], Rv[ee], Cr[kk][ee]);
          Ci[kk][ee] = fmaf(vik[kk], Rv[ee], Ci[kk][ee]);
          Dr[kk][ee] = fmaf(vrk[kk], Iv[ee], Dr[kk][ee]);
          Di[kk][ee] = fmaf(vik[kk], Iv[ee], Di[kk][ee]);
        }
    }
    #pragma unroll
    for (int kk = 0; kk < 4; kk++){
      float val = 0.f;
      #pragma unroll
      for (int ee = 0; ee < 4; ee++){
        float vre = VR[(k0+kk)*128 + e0 + ee];
        float vie = VI[(k0+kk)*128 + e0 + ee];
        val += vre * (Cr[kk][ee] + Di[kk][ee]) + vie * (Ci[kk][ee] - Dr[kk][ee]);
      }
      atomicAdd(&sp[k0+kk], val);
    }
  }
  __syncthreads();
  if (tid < 128) PROBS[(size_t)(z*256 + bt)*128 + tid] = sp[tid];
}

// ---------------------------------------------------------------------------
// Kernel 6: classifier head + log_softmax. grid 256 (bt), block 64
// ---------------------------------------------------------------------------
__global__ void head_kernel(const float* PROBS, const float* W1, const float* b1,
                            const float* W2, const float* b2, float* out)
{
  __shared__ float h[64];
  __shared__ float lg[7];
  __shared__ float mred[2];
  int bt = blockIdx.x, tid = threadIdx.x;
  float acc = b1[tid];
  for (int d = 0; d < 128; d++){
    float p = PROBS[bt*128 + d] + PROBS[(256+bt)*128 + d];
    acc = fmaf(p, W1[d*64 + tid], acc);
  }
  h[tid] = fmaxf(acc, 0.f);
  __syncthreads();
  if (tid < 7){
    float a = b2[tid];
    for (int j = 0; j < 64; j++) a = fmaf(h[j], W2[j*7 + tid], a);
    lg[tid] = a;
  }
  __syncthreads();
  if (tid == 0){
    float M = -1e30f;
    for (int c = 0; c < 7; c++) M = fmaxf(M, lg[c]);
    float S = 0.f;
    for (int c = 0; c < 7; c++) S += __expf(lg[c] - M);
    mred[0] = M; mred[1] = logf(S);
  }
  __syncthreads();
  if (tid < 7) out[bt*7 + tid] = lg[tid] - mred[0] - mred[1];
}

// ---------------------------------------------------------------------------
extern "C" void kernel_launch(void* const* d_in, const int* in_sizes, int n_in,
                              void* d_out, int out_size, void* d_ws, size_t ws_size,
                              hipStream_t stream)
{
  (void)in_sizes; (void)n_in; (void)out_size; (void)ws_size;
  const float* xt   = (const float*)d_in[0];
  const float* xv   = (const float*)d_in[1];
  const float* xa   = (const float*)d_in[2];
  const float* Wpt  = (const float*)d_in[3];
  const float* bpt  = (const float*)d_in[4];
  const float* Wpv  = (const float*)d_in[5];
  const float* bpv  = (const float*)d_in[6];
  const float* Wpa  = (const float*)d_in[7];
  const float* bpa  = (const float*)d_in[8];
  const float* l1   = (const float*)d_in[9];
  const float* l2   = (const float*)d_in[10];
  const float* Wl1  = (const float*)d_in[11];
  const float* bl1  = (const float*)d_in[12];
  const float* Wl2  = (const float*)d_in[13];
  const float* bl2  = (const float*)d_in[14];
  const float* pht  = (const float*)d_in[15];
  const float* phv  = (const float*)d_in[16];
  const float* pha  = (const float*)d_in[17];
  const float* Wqkv = (const float*)d_in[18];
  const float* bqkv = (const float*)d_in[19];
  const float* Wo   = (const float*)d_in[20];
  const float* bo   = (const float*)d_in[21];
  const float* g1   = (const float*)d_in[22];
  const float* b1   = (const float*)d_in[23];
  const float* W1   = (const float*)d_in[24];
  const float* bf1  = (const float*)d_in[25];
  const float* W2   = (const float*)d_in[26];
  const float* bf2  = (const float*)d_in[27];
  const float* g2   = (const float*)d_in[28];
  const float* b2   = (const float*)d_in[29];
  const float* mr   = (const float*)d_in[30];
  const float* mi   = (const float*)d_in[31];
  const float* fcW1 = (const float*)d_in[32];
  const float* fcb1 = (const float*)d_in[33];
  const float* fcW2 = (const float*)d_in[34];
  const float* fcb2 = (const float*)d_in[35];
  float* out = (float*)d_out;

  // workspace layout (bytes) -- total ~50.4 MiB.
  // NOTE: W1T/W2T hold TWO layers: 2 * 512*128 * 2B = 262144 B each
  // (rounds 5/6 under-allocated these at 131072 B -> layer-1 overflow = the bug)
  char* wsb = (char*)d_ws;
  float* X      = (float*)(wsb);                        // 33554432 B
  bf16*  ATTO   = (bf16*) (wsb + 33554432);             // 16777216 B
  float* PURE   = (float*)(wsb + 50331648);             // 786432 B
  float* RNORM  = (float*)(wsb + 51118080);             // 4096 B
  float* LANGB  = (float*)(wsb + 51122176);             // 2048 B
  float* VMEAS  = (float*)(wsb + 51124224);             // 131072 B
  float* PROBS  = (float*)(wsb + 51255296);             // 262144 B
  short* WqkvT  = (short*)(wsb + 51517440);             // 196608 B (2 layers)
  short* WoTh   = (short*)(wsb + 51714048);             // 65536 B  (2 layers)
  short* WoTl   = (short*)(wsb + 51779584);             // 65536 B  (2 layers)
  short* W1Th   = (short*)(wsb + 51845120);             // 262144 B (2 layers)
  short* W1Tl   = (short*)(wsb + 52107264);             // 262144 B (2 layers)
  short* W2Th   = (short*)(wsb + 52369408);             // 262144 B (2 layers)
  short* W2Tl   = (short*)(wsb + 52631552);             // 262144 B (2 layers)

  // weight prep (both layers per launch via blockIdx.y)
  wT_kernel <<<dim3(48, 2), 256, 0, stream>>>(Wqkv, WqkvT, 128, 384);
  wT2_kernel<<<dim3(16, 2), 256, 0, stream>>>(Wo, WoTh, WoTl, 128, 128);
  wT2_kernel<<<dim3(64, 2), 256, 0, stream>>>(W1, W1Th, W1Tl, 128, 512);
  wT2_kernel<<<dim3(64, 2), 256, 0, stream>>>(W2, W2Th, W2Tl, 512, 128);

  proj_kernel<<<256, 128, 0, stream>>>(xt, xv, xa, Wpt, bpt, Wpv, bpv, Wpa, bpa,
                                       pht, phv, pha, PURE, RNORM);
  lang_kernel<<<1, 128, 0, stream>>>(l1, l2, Wl1, bl1, Wl2, bl2, pht, LANGB);
  rho_kernel<<<256, 256, 0, stream>>>(PURE, RNORM, LANGB, X);

  for (int l = 0; l < 2; l++){
    attn_kernel<<<dim3(512, 4), 256, 0, stream>>>(X, WqkvT + (size_t)l*49152,
                                                  bqkv + (size_t)l*384, ATTO);
    proj_ln_kernel<<<512, 256, 0, stream>>>(ATTO, X,
                                            WoTh + (size_t)l*16384, WoTl + (size_t)l*16384,
                                            bo + (size_t)l*128, g1 + (size_t)l*128,
                                            b1 + (size_t)l*128);
    ffn_ln_kernel<<<512, 256, 0, stream>>>(X,
                                           W1Th + (size_t)l*65536, W1Tl + (size_t)l*65536,
                                           bf1 + (size_t)l*512,
                                           W2Th + (size_t)l*65536, W2Tl + (size_t)l*65536,
                                           bf2 + (size_t)l*128,
                                           g2 + (size_t)l*128, b2 + (size_t)l*128);
  }

  meas_norm_kernel<<<1, 128, 0, stream>>>(mr, mi, VMEAS);
  probs_kernel<<<dim3(256, 2), 256, 0, stream>>>(X, VMEAS, PROBS);
  head_kernel<<<256, 64, 0, stream>>>(PROBS, fcW1, fcb1, fcW2, fcb2, out);
}